// Round 6
// baseline (292.356 us; speedup 1.0000x reference)
//
#include <hip/hip_runtime.h>

// MoE: M=4096, K=1024, E=8, N=1024, TOPK=2
// out[m] = sum_t topk_w[m,t] * ( silu(hs[m]@w1[e][:, :N]) * (hs[m]@w1[e][:, N:]) ) @ w2[e]

#define M_TOK   4096
#define K_DIM   1024
#define N_DIM   1024
#define E_NUM   8
#define NPAIR   8192            // M_TOK * TOPK
#define BM      128
#define ROWS_CAP 9216           // NPAIR + E_NUM*BM
#define NROWBLK 72              // ROWS_CAP / BM  (divisible by 8 -> bijective XCD swizzle)

typedef unsigned short u16;
typedef unsigned int   u32;
typedef __attribute__((ext_vector_type(8))) short bf16x8;
typedef __attribute__((ext_vector_type(4))) float f32x4;

#define GPTR(p) ((const __attribute__((address_space(1))) u32*)(const void*)(p))
#define LPTR(p) ((__attribute__((address_space(3))) u32*)(void*)(p))

__device__ __forceinline__ u16 f2bf(float f) {
  union { float f; u32 u; } v; v.f = f;
  u32 r = v.u + 0x7FFFu + ((v.u >> 16) & 1u);   // RNE
  return (u16)(r >> 16);
}
__device__ __forceinline__ float bf2f(u16 u) {
  union { u32 u; float f; } v; v.u = ((u32)u) << 16;
  return v.f;
}

// ---------------- 64x64 fp32 (R,Cc) -> bf16 (Cc,R) transpose tile -------------
// LDS [64][67] f32: pad 67 -> write free, read 2-way max (free per m136).
__device__ __forceinline__ void transpose_tile64(
    const float* __restrict__ src, u16* __restrict__ dst, int R, int Cc,
    int rb, int cb, void* shm) {
  float* lds = (float*)shm;                  // [64][67]
  const int r0 = rb * 64, c0 = cb * 64;
  const int t = threadIdx.x;
#pragma unroll
  for (int it = 0; it < 4; ++it) {
    int lin = it * 256 + t;                  // 0..1023
    int rr = lin >> 4, c4 = (lin & 15) << 2;
    float4 v = *(const float4*)&src[(size_t)(r0 + rr) * Cc + c0 + c4];
    lds[rr * 67 + c4 + 0] = v.x; lds[rr * 67 + c4 + 1] = v.y;
    lds[rr * 67 + c4 + 2] = v.z; lds[rr * 67 + c4 + 3] = v.w;
  }
  __syncthreads();
#pragma unroll
  for (int it = 0; it < 4; ++it) {
    int lin = it * 256 + t;
    int cc = lin >> 4, r4 = (lin & 15) << 2;
    ushort4 o;
    o.x = f2bf(lds[(r4 + 0) * 67 + cc]);
    o.y = f2bf(lds[(r4 + 1) * 67 + cc]);
    o.z = f2bf(lds[(r4 + 2) * 67 + cc]);
    o.w = f2bf(lds[(r4 + 3) * 67 + cc]);
    *(ushort4*)&dst[(size_t)(c0 + cc) * R + r0 + r4] = o;
  }
}

// ---------------- fused prep: routing + hs convert + out zero + transposes ----
// (r5 lesson: w2t co-dispatched with GEMM1 produced intermittent divergence --
//  reverted to the r4-proven all-in-prep structure. Do not retry without a
//  multi-run race screen.)
// block 0            : routing (single block, deterministic p-order positions);
//                      also emits coef_of[pos] (0 for pad rows) for the fused
//                      GEMM2 scatter epilogue.
// blocks 1..4096     : hs fp32 -> bf16 flat convert + zero out (float4/lane)
// blocks 4097..8192  : w1 (E,K,2N) f32 -> w1t (E,2N,K) bf16 transpose tiles
// blocks 8193..10240 : w2 (E,N,K)  f32 -> w2t (E,K,N)  bf16 transpose tiles
__global__ __launch_bounds__(256) void prep_route_kernel(
    const float* __restrict__ hs, const float* __restrict__ w1,
    const float* __restrict__ w2, const float* __restrict__ tw,
    const int* __restrict__ topk_ids,
    u16* __restrict__ hsb, u16* __restrict__ w1t, u16* __restrict__ w2t,
    float* __restrict__ outf,
    int* __restrict__ pair_token, float* __restrict__ coef_of,
    int* __restrict__ block_expert) {
  __shared__ __align__(16) char shm[17408];
  const int bid = blockIdx.x;
  const int t = threadIdx.x;
  if (bid == 0) {
    // ---- routing: hist + scan + assign, fused in one block ----
    int* lcnt = (int*)shm;                   // [256][8] per-thread expert counts
    __shared__ int cnt[E_NUM], off[E_NUM], pad[E_NUM];
    int c[E_NUM];
#pragma unroll
    for (int e = 0; e < E_NUM; ++e) c[e] = 0;
    // thread t owns pairs [t*32, t*32+32) -> deterministic p-order
    for (int i = 0; i < 32; ++i) c[topk_ids[t * 32 + i] & 7]++;
#pragma unroll
    for (int e = 0; e < E_NUM; ++e) lcnt[t * 8 + e] = c[e];
    __syncthreads();
    if (t < E_NUM) {                         // serial exclusive scan per expert
      int run = 0;
      for (int i = 0; i < 256; ++i) {
        int v = lcnt[i * 8 + t]; lcnt[i * 8 + t] = run; run += v;
      }
      cnt[t] = run;
    }
    __syncthreads();
    if (t == 0) {
      int run = 0, blk = 0;
      for (int e = 0; e < E_NUM; ++e) {
        off[e] = run;
        int padded = ((cnt[e] + BM - 1) / BM) * BM;
        pad[e] = padded;
        for (int b = 0; b < padded / BM; ++b) block_expert[blk++] = e;
        run += padded;
      }
      for (; blk < NROWBLK; ++blk) block_expert[blk] = -1;
    }
    __syncthreads();
    // assign: running counter per (thread, expert) in LDS
    for (int i = 0; i < 32; ++i) {
      int p = t * 32 + i;
      int e = topk_ids[p] & 7;
      int idx = t * 8 + e;
      int pos = off[e] + lcnt[idx];
      lcnt[idx] = lcnt[idx] + 1;
      pair_token[pos] = p >> 1;
      coef_of[pos] = tw[p];
    }
    // pad rows: point at token 0 (computed, never accumulated: coef 0)
    for (int e = 0; e < E_NUM; ++e) {
      int s = off[e] + cnt[e], epos = off[e] + pad[e];
      for (int r = s + t; r < epos; r += 256) { pair_token[r] = 0; coef_of[r] = 0.f; }
    }
  } else if (bid <= 4096) {
    // ---- hs convert + out zero (same index space: M*K == M*1024 f32) ----
    int i = (bid - 1) * 256 + t;
    float4 v = ((const float4*)hs)[i];
    ushort4 o;
    o.x = f2bf(v.x); o.y = f2bf(v.y); o.z = f2bf(v.z); o.w = f2bf(v.w);
    ((ushort4*)hsb)[i] = o;
    ((float4*)outf)[i] = float4{0.f, 0.f, 0.f, 0.f};
  } else if (bid <= 8192) {
    // ---- w1 transpose: R=1024(K), Cc=2048(2N); 512 tiles/expert ----
    int idx = bid - 4097;
    int e = idx >> 9, rem = idx & 511;
    int cb = rem >> 4, rb = rem & 15;
    transpose_tile64(w1 + (size_t)e * 1024 * 2048, w1t + (size_t)e * 1024 * 2048,
                     1024, 2048, rb, cb, shm);
  } else {
    // ---- w2 transpose: R=1024(N), Cc=1024(K); 256 tiles/expert ----
    int idx = bid - 8193;
    int e = idx >> 8, rem = idx & 255;
    int cb = rem >> 4, rb = rem & 15;
    transpose_tile64(w2 + (size_t)e * 1024 * 1024, w2t + (size_t)e * 1024 * 1024,
                     1024, 1024, rb, cb, shm);
  }
}

// ---------------- grouped GEMM, 128x128 tile, NB B-matrices -------------------
// NB=2: fused gate|up GEMM1 -> h = silu(gate)*up (bf16 store to h).
// NB=1 + SCATTER: GEMM2 with fused gather -- epilogue does
//   atomicAdd(&out[token*1024+col], coef*v). Exactly TOPK=2 contributions per
//   output element; 2-way f32 add is commutative -> bit-deterministic. Pad rows
//   contribute coef=0 -> exact identity. Also skips the bf16 y round-trip.
// Round-2 winner schedule (57.4us GEMM1 at the 2-phase structural ceiling
// ~673 TF): 4 waves 2x2, wave 64x64(xNB), acc[NB][4][4], single-buffered drain
// (2ph dbuf r1 and narrow 8ph counted-vmcnt r3 both proven non-better here).
// Zero-conflict XOR-swizzle staging via global_load_lds width=16.
// XCD chunk swizzle (T1): 72 % 8 == 0 -> bx = (b&7)*9 + (b>>3) bijective.
template <bool GATHER, int NB, bool SCATTER>
__global__ __launch_bounds__(256, NB == 2 ? 2 : 3) void gemm128(
    const u16* __restrict__ A, const u16* __restrict__ Bt, u16* __restrict__ Out,
    const int* __restrict__ pair_token, const int* __restrict__ block_expert,
    const float* __restrict__ coef_of, float* __restrict__ outf) {
  const int bx = ((int)blockIdx.x & 7) * (NROWBLK / 8) + ((int)blockIdx.x >> 3);
  const int e = block_expert[bx];
  if (e < 0) return;
  __shared__ __align__(16) u16 As[128 * 64];
  __shared__ __align__(16) u16 Bs[NB * 128 * 64];
  const int tid = threadIdx.x;
  const int wave = tid >> 6;
  const int lane = tid & 63;
  const int wr = wave >> 1;                  // wave row-group (0..1)
  const int wc = wave & 1;                   // wave col-group (0..1)
  const int srow = wave * 8 + (lane >> 3);   // staging row within 32-row shot
  const int kc = ((lane & 7) ^ (srow & 7)) << 3;  // swizzled src chunk (elems)

  const u16* ap[4];
#pragma unroll
  for (int is = 0; is < 4; ++is) {
    int rt = is * 32 + srow;
    int grow = bx * BM + rt;
    int arow = GATHER ? pair_token[grow] : grow;
    ap[is] = A + (size_t)arow * K_DIM + kc;
  }
  const u16* bp[NB][4];
  const u16* base_e = Bt + (size_t)e * (NB * N_DIM) * K_DIM;
#pragma unroll
  for (int nb = 0; nb < NB; ++nb)
#pragma unroll
    for (int is = 0; is < 4; ++is) {
      int n = nb * N_DIM + blockIdx.y * 128 + is * 32 + srow;
      bp[nb][is] = base_e + (size_t)n * K_DIM + kc;
    }
  u16* alds = As + wave * 512;
  u16* blds = Bs + wave * 512;

  f32x4 acc[NB][4][4];
#pragma unroll
  for (int nb = 0; nb < NB; ++nb)
#pragma unroll
    for (int i = 0; i < 4; ++i)
#pragma unroll
      for (int j = 0; j < 4; ++j) acc[nb][i][j] = f32x4{0.f, 0.f, 0.f, 0.f};

  for (int k0 = 0; k0 < K_DIM; k0 += 64) {
#pragma unroll
    for (int is = 0; is < 4; ++is)
      __builtin_amdgcn_global_load_lds(GPTR(ap[is] + k0), LPTR(alds + is * 2048), 16, 0, 0);
#pragma unroll
    for (int nb = 0; nb < NB; ++nb)
#pragma unroll
      for (int is = 0; is < 4; ++is)
        __builtin_amdgcn_global_load_lds(GPTR(bp[nb][is] + k0), LPTR(blds + nb * 8192 + is * 2048), 16, 0, 0);
    __syncthreads();
#pragma unroll
    for (int ks = 0; ks < 2; ++ks) {
      const int cq = ks * 4 + (lane >> 4);
      bf16x8 af[4], bfr[NB][4];
#pragma unroll
      for (int i = 0; i < 4; ++i) {
        int row = wr * 64 + i * 16 + (lane & 15);
        af[i] = *(const bf16x8*)&As[row * 64 + ((cq ^ (row & 7)) << 3)];
      }
#pragma unroll
      for (int nb = 0; nb < NB; ++nb)
#pragma unroll
        for (int j = 0; j < 4; ++j) {
          int n = wc * 64 + j * 16 + (lane & 15);
          bfr[nb][j] = *(const bf16x8*)&Bs[nb * 8192 + n * 64 + ((cq ^ (n & 7)) << 3)];
        }
#pragma unroll
      for (int nb = 0; nb < NB; ++nb)
#pragma unroll
        for (int i = 0; i < 4; ++i)
#pragma unroll
          for (int j = 0; j < 4; ++j)
            acc[nb][i][j] = __builtin_amdgcn_mfma_f32_16x16x32_bf16(af[i], bfr[nb][j], acc[nb][i][j], 0, 0, 0);
    }
    __syncthreads();
  }

  // epilogue: C/D layout col=lane&15, row=(lane>>4)*4+reg (m89/m91-verified)
  const size_t rbase = (size_t)bx * BM + wr * 64 + ((lane >> 4) * 4);
  const int cbase = blockIdx.y * 128 + wc * 64 + (lane & 15);
  if constexpr (SCATTER) {
#pragma unroll
    for (int i = 0; i < 4; ++i)
#pragma unroll
      for (int r = 0; r < 4; ++r) {
        const int row = (int)rbase + i * 16 + r;
        const int tok = pair_token[row];
        const float cf = coef_of[row];
        float* orow = outf + (size_t)tok * N_DIM + cbase;
#pragma unroll
        for (int j = 0; j < 4; ++j)
          atomicAdd(&orow[j * 16], cf * acc[0][i][j][r]);
      }
  } else {
#pragma unroll
    for (int i = 0; i < 4; ++i)
#pragma unroll
      for (int j = 0; j < 4; ++j)
#pragma unroll
        for (int r = 0; r < 4; ++r) {
          float v;
          if (NB == 2) {
            float g = acc[0][i][j][r], u = acc[1][i][j][r];
            v = g * u / (1.f + __expf(-g));
          } else {
            v = acc[0][i][j][r];
          }
          Out[(rbase + i * 16 + r) * N_DIM + cbase + j * 16] = f2bf(v);
        }
  }
}

extern "C" void kernel_launch(void* const* d_in, const int* in_sizes, int n_in,
                              void* d_out, int out_size, void* d_ws, size_t ws_size,
                              hipStream_t stream) {
  const float* hs = (const float*)d_in[0];
  const float* w1 = (const float*)d_in[1];
  const float* w2 = (const float*)d_in[2];
  const float* tw = (const float*)d_in[3];
  const int* tids = (const int*)d_in[4];
  float* out = (float*)d_out;

  char* ws = (char*)d_ws;
  u16* hsb = (u16*)(ws);                                 //  8 MB  (M,K) bf16
  u16* w1t = (u16*)(ws + (size_t)(8u << 20));            // 32 MB  (E,2N,K) bf16
  u16* w2t = (u16*)(ws + (size_t)(40u << 20));           // 16 MB  (E,K,N)  bf16
  u16* h   = (u16*)(ws + (size_t)(56u << 20));           // 18.9 MB (ROWS_CAP,N)
  int* pair_token   = (int*)(ws + (size_t)(96u << 20));
  float* coef_of    = (float*)(ws + (size_t)(96u << 20) + 64 * 1024);
  int* block_expert = (int*)(ws + (size_t)(96u << 20) + 128 * 1024);

  // 3 dispatches: prep (routing+zero+hsb+w1t+w2t), GEMM1, GEMM2(+fused gather)
  prep_route_kernel<<<10241, 256, 0, stream>>>(
      hs, w1, w2, tw, tids, hsb, w1t, w2t, out, pair_token, coef_of, block_expert);
  gemm128<true, 2, false><<<dim3(NROWBLK, 8), 256, 0, stream>>>(
      hsb, w1t, h, pair_token, block_expert, nullptr, nullptr);
  gemm128<false, 1, true><<<dim3(NROWBLK, 8), 256, 0, stream>>>(
      h, w2t, nullptr, pair_token, block_expert, coef_of, out);
}

// Round 7
// 238.815 us; speedup vs baseline: 1.2242x; 1.2242x over previous
//
#include <hip/hip_runtime.h>

// MoE: M=4096, K=1024, E=8, N=1024, TOPK=2
// out[m] = sum_t topk_w[m,t] * ( silu(hs[m]@w1[e][:, :N]) * (hs[m]@w1[e][:, N:]) ) @ w2[e]
//
// Session ledger (r0-r6): total ~= sum(kernels) + ~100us fixed residual.
// Proven: XCD swizzle (FETCH 163->42MB), launch fusion 9->4 (-16us),
//         128-tile (neutral time, less traffic). r4 = 235.9us frontier.
// Disproven HERE: 2ph dbuf (r1 null), narrow 8ph counted-vmcnt (r3 -9us),
//         gemm||transpose co-dispatch (r5 intermittent diverge -- radioactive),
//         atomic scatter epilogue (r6 -56us).

#define M_TOK   4096
#define K_DIM   1024
#define N_DIM   1024
#define E_NUM   8
#define NPAIR   8192            // M_TOK * TOPK
#define BM      128
#define ROWS_CAP 9216           // NPAIR + E_NUM*BM
#define NROWBLK 72              // ROWS_CAP / BM  (divisible by 8 -> bijective XCD swizzle)

typedef unsigned short u16;
typedef unsigned int   u32;
typedef __attribute__((ext_vector_type(8))) short bf16x8;
typedef __attribute__((ext_vector_type(8))) unsigned short ushort8;
typedef __attribute__((ext_vector_type(4))) float f32x4;

#define GPTR(p) ((const __attribute__((address_space(1))) u32*)(const void*)(p))
#define LPTR(p) ((__attribute__((address_space(3))) u32*)(void*)(p))

__device__ __forceinline__ u16 f2bf(float f) {
  union { float f; u32 u; } v; v.f = f;
  u32 r = v.u + 0x7FFFu + ((v.u >> 16) & 1u);   // RNE
  return (u16)(r >> 16);
}
__device__ __forceinline__ float bf2f(u16 u) {
  union { u32 u; float f; } v; v.u = ((u32)u) << 16;
  return v.f;
}

// ---------------- 64x64 fp32 (R,Cc) -> bf16 (Cc,R) transpose tile -------------
// Read: float4/lane coalesced. LDS [64][67] f32 (pad 67 -> <=2-way, free m136).
// Write: ushort8/lane (16B) -- lane covers 8 dst-contiguous rows; 8 lanes
// complete one 128B column. LDS read stride 8*67=536 -> banks {0,24,16,8}x2
// over 8 lanes = 2-way (free).
__device__ __forceinline__ void transpose_tile64(
    const float* __restrict__ src, u16* __restrict__ dst, int R, int Cc,
    int rb, int cb, void* shm) {
  float* lds = (float*)shm;                  // [64][67]
  const int r0 = rb * 64, c0 = cb * 64;
  const int t = threadIdx.x;
#pragma unroll
  for (int it = 0; it < 4; ++it) {
    int lin = it * 256 + t;                  // 0..1023
    int rr = lin >> 4, c4 = (lin & 15) << 2;
    float4 v = *(const float4*)&src[(size_t)(r0 + rr) * Cc + c0 + c4];
    lds[rr * 67 + c4 + 0] = v.x; lds[rr * 67 + c4 + 1] = v.y;
    lds[rr * 67 + c4 + 2] = v.z; lds[rr * 67 + c4 + 3] = v.w;
  }
  __syncthreads();
#pragma unroll
  for (int it = 0; it < 2; ++it) {
    int lin = it * 256 + t;                  // 0..511
    int cc = lin >> 3, r8 = (lin & 7) << 3;
    ushort8 o;
#pragma unroll
    for (int j = 0; j < 8; ++j) o[j] = f2bf(lds[(r8 + j) * 67 + cc]);
    *(ushort8*)&dst[(size_t)(c0 + cc) * R + r0 + r8] = o;
  }
}

// ---------------- fused prep: routing + hs convert + w1/w2 transposes ---------
// block 0            : routing (single block, deterministic p-order positions)
// blocks 1..4096     : hs fp32 -> bf16 flat convert (float4/lane)
// blocks 4097..8192  : w1 (E,K,2N) f32 -> w1t (E,2N,K) bf16 transpose tiles
// blocks 8193..10240 : w2 (E,N,K)  f32 -> w2t (E,K,N)  bf16 transpose tiles
__global__ __launch_bounds__(256) void prep_route_kernel(
    const float* __restrict__ hs, const float* __restrict__ w1,
    const float* __restrict__ w2, const int* __restrict__ topk_ids,
    u16* __restrict__ hsb, u16* __restrict__ w1t, u16* __restrict__ w2t,
    int* __restrict__ pair_token, int* __restrict__ pos_of,
    int* __restrict__ block_expert) {
  __shared__ __align__(16) char shm[17408];
  const int bid = blockIdx.x;
  const int t = threadIdx.x;
  if (bid == 0) {
    // ---- routing: hist + scan + assign, fused in one block ----
    int* lcnt = (int*)shm;                   // [256][8] per-thread expert counts
    __shared__ int cnt[E_NUM], off[E_NUM], pad[E_NUM];
    int c[E_NUM];
#pragma unroll
    for (int e = 0; e < E_NUM; ++e) c[e] = 0;
    // thread t owns pairs [t*32, t*32+32) -> deterministic p-order
    for (int i = 0; i < 32; ++i) c[topk_ids[t * 32 + i] & 7]++;
#pragma unroll
    for (int e = 0; e < E_NUM; ++e) lcnt[t * 8 + e] = c[e];
    __syncthreads();
    if (t < E_NUM) {                         // serial exclusive scan per expert
      int run = 0;
      for (int i = 0; i < 256; ++i) {
        int v = lcnt[i * 8 + t]; lcnt[i * 8 + t] = run; run += v;
      }
      cnt[t] = run;
    }
    __syncthreads();
    if (t == 0) {
      int run = 0, blk = 0;
      for (int e = 0; e < E_NUM; ++e) {
        off[e] = run;
        int padded = ((cnt[e] + BM - 1) / BM) * BM;
        pad[e] = padded;
        for (int b = 0; b < padded / BM; ++b) block_expert[blk++] = e;
        run += padded;
      }
      for (; blk < NROWBLK; ++blk) block_expert[blk] = -1;
    }
    __syncthreads();
    // assign: running counter per (thread, expert) in LDS
    for (int i = 0; i < 32; ++i) {
      int p = t * 32 + i;
      int e = topk_ids[p] & 7;
      int idx = t * 8 + e;
      int pos = off[e] + lcnt[idx];
      lcnt[idx] = lcnt[idx] + 1;
      pair_token[pos] = p >> 1;
      pos_of[p] = pos;
    }
    // pad rows point at token 0 (computed, never gathered)
    for (int e = 0; e < E_NUM; ++e) {
      int s = off[e] + cnt[e], epos = off[e] + pad[e];
      for (int r = s + t; r < epos; r += 256) pair_token[r] = 0;
    }
  } else if (bid <= 4096) {
    // ---- hs convert ----
    int i = (bid - 1) * 256 + t;
    float4 v = ((const float4*)hs)[i];
    ushort4 o;
    o.x = f2bf(v.x); o.y = f2bf(v.y); o.z = f2bf(v.z); o.w = f2bf(v.w);
    ((ushort4*)hsb)[i] = o;
  } else if (bid <= 8192) {
    // ---- w1 transpose: R=1024(K), Cc=2048(2N); 512 tiles/expert ----
    int idx = bid - 4097;
    int e = idx >> 9, rem = idx & 511;
    int cb = rem >> 4, rb = rem & 15;
    transpose_tile64(w1 + (size_t)e * 1024 * 2048, w1t + (size_t)e * 1024 * 2048,
                     1024, 2048, rb, cb, shm);
  } else {
    // ---- w2 transpose: R=1024(N), Cc=1024(K); 256 tiles/expert ----
    int idx = bid - 8193;
    int e = idx >> 8, rem = idx & 255;
    int cb = rem >> 4, rb = rem & 15;
    transpose_tile64(w2 + (size_t)e * 1024 * 1024, w2t + (size_t)e * 1024 * 1024,
                     1024, 1024, rb, cb, shm);
  }
}

// ---------------- grouped GEMM, 128x128 tile, NB B-matrices -------------------
// NB=2: fused gate|up GEMM1 -> h = silu(gate)*up.  NB=1: plain GEMM2 -> y.
// Round-2/4 winner schedule (57-59us GEMM1 at the 2-phase structural ceiling
// ~673 TF): 4 waves 2x2, wave 64x64(xNB), acc[NB][4][4], single-buffered drain
// (dbuf r1 / narrow 8ph r3 / atomic epilogue r6 all proven non-better here).
// Zero-conflict XOR-swizzle staging via global_load_lds width=16.
// XCD chunk swizzle (T1): 72 % 8 == 0 -> bx = (b&7)*9 + (b>>3) bijective.
template <bool GATHER, int NB>
__global__ __launch_bounds__(256, NB == 2 ? 2 : 3) void gemm128(
    const u16* __restrict__ A, const u16* __restrict__ Bt, u16* __restrict__ Out,
    const int* __restrict__ pair_token, const int* __restrict__ block_expert) {
  const int bx = ((int)blockIdx.x & 7) * (NROWBLK / 8) + ((int)blockIdx.x >> 3);
  const int e = block_expert[bx];
  if (e < 0) return;
  __shared__ __align__(16) u16 As[128 * 64];
  __shared__ __align__(16) u16 Bs[NB * 128 * 64];
  const int tid = threadIdx.x;
  const int wave = tid >> 6;
  const int lane = tid & 63;
  const int wr = wave >> 1;                  // wave row-group (0..1)
  const int wc = wave & 1;                   // wave col-group (0..1)
  const int srow = wave * 8 + (lane >> 3);   // staging row within 32-row shot
  const int kc = ((lane & 7) ^ (srow & 7)) << 3;  // swizzled src chunk (elems)

  const u16* ap[4];
#pragma unroll
  for (int is = 0; is < 4; ++is) {
    int rt = is * 32 + srow;
    int grow = bx * BM + rt;
    int arow = GATHER ? pair_token[grow] : grow;
    ap[is] = A + (size_t)arow * K_DIM + kc;
  }
  const u16* bp[NB][4];
  const u16* base_e = Bt + (size_t)e * (NB * N_DIM) * K_DIM;
#pragma unroll
  for (int nb = 0; nb < NB; ++nb)
#pragma unroll
    for (int is = 0; is < 4; ++is) {
      int n = nb * N_DIM + blockIdx.y * 128 + is * 32 + srow;
      bp[nb][is] = base_e + (size_t)n * K_DIM + kc;
    }
  u16* alds = As + wave * 512;
  u16* blds = Bs + wave * 512;

  f32x4 acc[NB][4][4];
#pragma unroll
  for (int nb = 0; nb < NB; ++nb)
#pragma unroll
    for (int i = 0; i < 4; ++i)
#pragma unroll
      for (int j = 0; j < 4; ++j) acc[nb][i][j] = f32x4{0.f, 0.f, 0.f, 0.f};

  for (int k0 = 0; k0 < K_DIM; k0 += 64) {
#pragma unroll
    for (int is = 0; is < 4; ++is)
      __builtin_amdgcn_global_load_lds(GPTR(ap[is] + k0), LPTR(alds + is * 2048), 16, 0, 0);
#pragma unroll
    for (int nb = 0; nb < NB; ++nb)
#pragma unroll
      for (int is = 0; is < 4; ++is)
        __builtin_amdgcn_global_load_lds(GPTR(bp[nb][is] + k0), LPTR(blds + nb * 8192 + is * 2048), 16, 0, 0);
    __syncthreads();
#pragma unroll
    for (int ks = 0; ks < 2; ++ks) {
      const int cq = ks * 4 + (lane >> 4);
      bf16x8 af[4], bfr[NB][4];
#pragma unroll
      for (int i = 0; i < 4; ++i) {
        int row = wr * 64 + i * 16 + (lane & 15);
        af[i] = *(const bf16x8*)&As[row * 64 + ((cq ^ (row & 7)) << 3)];
      }
#pragma unroll
      for (int nb = 0; nb < NB; ++nb)
#pragma unroll
        for (int j = 0; j < 4; ++j) {
          int n = wc * 64 + j * 16 + (lane & 15);
          bfr[nb][j] = *(const bf16x8*)&Bs[nb * 8192 + n * 64 + ((cq ^ (n & 7)) << 3)];
        }
#pragma unroll
      for (int nb = 0; nb < NB; ++nb)
#pragma unroll
        for (int i = 0; i < 4; ++i)
#pragma unroll
          for (int j = 0; j < 4; ++j)
            acc[nb][i][j] = __builtin_amdgcn_mfma_f32_16x16x32_bf16(af[i], bfr[nb][j], acc[nb][i][j], 0, 0, 0);
    }
    __syncthreads();
  }

  // epilogue: C/D layout col=lane&15, row=(lane>>4)*4+reg (m89/m91-verified)
  const size_t rbase = (size_t)bx * BM + wr * 64 + ((lane >> 4) * 4);
  const int cbase = blockIdx.y * 128 + wc * 64 + (lane & 15);
#pragma unroll
  for (int i = 0; i < 4; ++i)
#pragma unroll
    for (int j = 0; j < 4; ++j)
#pragma unroll
      for (int r = 0; r < 4; ++r) {
        float v;
        if (NB == 2) {
          float g = acc[0][i][j][r], u = acc[1][i][j][r];
          v = g * u / (1.f + __expf(-g));
        } else {
          v = acc[0][i][j][r];
        }
        Out[(rbase + i * 16 + r) * N_DIM + cbase + j * 16] = f2bf(v);
      }
}

// ---------------- gather: out[m] = w0*y[pos0] + w1*y[pos1] --------------------
__global__ __launch_bounds__(256) void gather_kernel(
    const u16* __restrict__ y, const float* __restrict__ tw,
    const int* __restrict__ pos_of, float* __restrict__ out) {
  int m = blockIdx.x;
  int k = threadIdx.x * 4;
  int p0 = pos_of[m * 2 + 0], p1 = pos_of[m * 2 + 1];
  float w0 = tw[m * 2 + 0], w1 = tw[m * 2 + 1];
  ushort4 y0 = *(const ushort4*)&y[(size_t)p0 * 1024 + k];
  ushort4 y1 = *(const ushort4*)&y[(size_t)p1 * 1024 + k];
  float4 o;
  o.x = w0 * bf2f(y0.x) + w1 * bf2f(y1.x);
  o.y = w0 * bf2f(y0.y) + w1 * bf2f(y1.y);
  o.z = w0 * bf2f(y0.z) + w1 * bf2f(y1.z);
  o.w = w0 * bf2f(y0.w) + w1 * bf2f(y1.w);
  *(float4*)&out[(size_t)m * 1024 + k] = o;
}

extern "C" void kernel_launch(void* const* d_in, const int* in_sizes, int n_in,
                              void* d_out, int out_size, void* d_ws, size_t ws_size,
                              hipStream_t stream) {
  const float* hs = (const float*)d_in[0];
  const float* w1 = (const float*)d_in[1];
  const float* w2 = (const float*)d_in[2];
  const float* tw = (const float*)d_in[3];
  const int* tids = (const int*)d_in[4];
  float* out = (float*)d_out;

  char* ws = (char*)d_ws;
  u16* hsb = (u16*)(ws);                                 //  8 MB  (M,K) bf16
  u16* w1t = (u16*)(ws + (size_t)(8u << 20));            // 32 MB  (E,2N,K) bf16
  u16* w2t = (u16*)(ws + (size_t)(40u << 20));           // 16 MB  (E,K,N)  bf16
  u16* h   = (u16*)(ws + (size_t)(56u << 20));           // 18.9 MB (ROWS_CAP,N)
  u16* y   = (u16*)(ws + (size_t)(76u << 20));           // 18.9 MB (ROWS_CAP,K)
  int* pair_token   = (int*)(ws + (size_t)(96u << 20));
  int* pos_of       = (int*)(ws + (size_t)(96u << 20) + 64 * 1024);
  int* block_expert = (int*)(ws + (size_t)(96u << 20) + 128 * 1024);

  // 4 dispatches (r4-proven structure): prep, GEMM1, GEMM2, gather
  prep_route_kernel<<<10241, 256, 0, stream>>>(
      hs, w1, w2, tids, hsb, w1t, w2t, pair_token, pos_of, block_expert);
  gemm128<true, 2><<<dim3(NROWBLK, 8), 256, 0, stream>>>(hsb, w1t, h, pair_token, block_expert);
  gemm128<false, 1><<<dim3(NROWBLK, 8), 256, 0, stream>>>(h, w2t, y, pair_token, block_expert);
  gather_kernel<<<4096, 256, 0, stream>>>(y, tw, pos_of, out);
}